// Round 8
// baseline (383.896 us; speedup 1.0000x reference)
//
#include <hip/hip_runtime.h>

#define N_NODES 100000
#define N_EDGES 600000
#define K_DIM   128
#define NPART   ((N_NODES + 255) / 256)   // 391 scan blocks

typedef unsigned short ushort_t;
typedef short v8s __attribute__((ext_vector_type(8)));   // 8 bf16 = 4 VGPRs
typedef float v4f __attribute__((ext_vector_type(4)));   // MFMA acc frag

// fp32 -> bf16 round-to-nearest-even (inputs are finite; no NaN handling)
__device__ __forceinline__ ushort_t f2b(float f) {
  unsigned u = __builtin_bit_cast(unsigned, f);
  unsigned r = u + 0x7FFFu + ((u >> 16) & 1u);
  return (ushort_t)(r >> 16);
}
__device__ __forceinline__ float b2f(ushort_t h) {
  return __builtin_bit_cast(float, (unsigned)h << 16);
}
// unpack a uint holding two bf16 (little-endian: element0 = low half)
__device__ __forceinline__ float blo(unsigned u) {
  return __builtin_bit_cast(float, u << 16);
}
__device__ __forceinline__ float bhi(unsigned u) {
  return __builtin_bit_cast(float, u & 0xFFFF0000u);
}

// ---------------------------------------------------------------- CSR build

__global__ void deg_kernel(const int* __restrict__ dst, int* __restrict__ deg) {
  int e = blockIdx.x * blockDim.x + threadIdx.x;
  if (e < N_EDGES) atomicAdd(&deg[dst[e]], 1);
}

__global__ void scan1_kernel(const int* __restrict__ deg, int* __restrict__ excl,
                             int* __restrict__ partials) {
  __shared__ int s[256];
  int t = threadIdx.x, i = blockIdx.x * 256 + t;
  int v = (i < N_NODES) ? deg[i] : 0;
  s[t] = v;
  __syncthreads();
  for (int off = 1; off < 256; off <<= 1) {
    int x = (t >= off) ? s[t - off] : 0;
    __syncthreads();
    s[t] += x;
    __syncthreads();
  }
  if (i < N_NODES) excl[i] = s[t] - v;
  if (t == 255) partials[blockIdx.x] = s[t];
}

__global__ void scan2_kernel(int* __restrict__ partials) {
  __shared__ int s[512];
  int t = threadIdx.x;
  int v = (t < NPART) ? partials[t] : 0;
  s[t] = v;
  __syncthreads();
  for (int off = 1; off < 512; off <<= 1) {
    int x = (t >= off) ? s[t - off] : 0;
    __syncthreads();
    s[t] += x;
    __syncthreads();
  }
  if (t < NPART) partials[t] = s[t] - v;   // exclusive block offsets
}

__global__ void scan3_kernel(const int* __restrict__ excl, const int* __restrict__ partials,
                             const int* __restrict__ deg, int* __restrict__ row_ptr,
                             int* __restrict__ cursor, float* __restrict__ inv_deg) {
  int i = blockIdx.x * blockDim.x + threadIdx.x;
  if (i < N_NODES) {
    int rp = excl[i] + partials[i >> 8];
    row_ptr[i] = rp;
    cursor[i] = rp;
    inv_deg[i] = 1.0f / (float)(deg[i] > 1 ? deg[i] : 1);
  } else if (i == N_NODES) {
    row_ptr[N_NODES] = N_EDGES;
  }
}

__global__ void fill_kernel(const int* __restrict__ src, const int* __restrict__ dst,
                            int* __restrict__ cursor, int* __restrict__ ssrc) {
  int e = blockIdx.x * blockDim.x + threadIdx.x;
  if (e < N_EDGES) {
    int p = atomicAdd(&cursor[dst[e]], 1);
    ssrc[p] = src[e];
  }
}

// ---------------------------------------------------------------- prep

// x (fp32) -> bf16 plane
__global__ void cast_kernel(const float* __restrict__ X, ushort_t* __restrict__ Xb) {
  int i = (blockIdx.x * 256 + threadIdx.x) * 4;
  if (i >= N_NODES * K_DIM) return;
  float4 v = *(const float4*)(X + i);
  ushort4 h;
  h.x = f2b(v.x); h.y = f2b(v.y); h.z = f2b(v.z); h.w = f2b(v.w);
  *(ushort4*)(Xb + i) = h;
}

// All 8 weights swizzled in ONE launch (blockIdx.z selects the weight).
// Layout: sw[(k>>3)*DOUT*8 + n*8 + (k&7)] -> lane's 8 k-values contiguous.
__global__ void swizzle_all_kernel(
    const float* __restrict__ w0, const float* __restrict__ w1,
    const float* __restrict__ w2, const float* __restrict__ w3,
    const float* __restrict__ w4, const float* __restrict__ w5,
    const float* __restrict__ w6, const float* __restrict__ w7,
    ushort_t* __restrict__ s0, ushort_t* __restrict__ s1,
    ushort_t* __restrict__ s2, ushort_t* __restrict__ s3,
    ushort_t* __restrict__ s4, ushort_t* __restrict__ s5,
    ushort_t* __restrict__ s6, ushort_t* __restrict__ s7) {
  const int z = blockIdx.z;
  const float* W;
  ushort_t* S;
  int dout = 128;
  switch (z) {
    case 0: W = w0; S = s0; break;
    case 1: W = w1; S = s1; break;
    case 2: W = w2; S = s2; break;
    case 3: W = w3; S = s3; break;
    case 4: W = w4; S = s4; break;
    case 5: W = w5; S = s5; break;
    case 6: W = w6; S = s6; dout = 64; break;
    default: W = w7; S = s7; dout = 64; break;
  }
  int t = blockIdx.x * 256 + threadIdx.x;
  if (t >= K_DIM * dout) return;
  int k = t / dout, n = t % dout;
  S[(k >> 3) * (dout * 8) + n * 8 + (k & 7)] = f2b(W[t]);
}

// ---------------------------------------------------------------- aggregate
// AGG[v] = inv_deg[v] * sum_{u->v} H[u]  (bf16 in, bf16 out -- single plane).
// 8 lanes/row (16 cols each), 32 rows/block, 2-edge unroll for MLP,
// max-occupancy launch bounds (VGPR 28 -> 8 waves/EU fits).

__global__ __launch_bounds__(256, 8) void agg_kernel(
    const ushort_t* __restrict__ Hh,
    const int* __restrict__ row_ptr, const int* __restrict__ ssrc,
    const float* __restrict__ inv_deg, ushort_t* __restrict__ Ah) {
  const int tid = threadIdx.x;
  const int c0  = (tid & 7) * 16;   // 16 columns per lane
  const int r   = tid >> 3;
  const int v   = blockIdx.x * 32 + r;
  if (v >= N_NODES) return;

  float a[16];
  #pragma unroll
  for (int i = 0; i < 16; ++i) a[i] = 0.f;

  const int beg = row_ptr[v], end = row_ptr[v + 1];
  int e = beg;
  for (; e + 2 <= end; e += 2) {
    const size_t r0 = (size_t)ssrc[e] * K_DIM + c0;
    const size_t r1 = (size_t)ssrc[e + 1] * K_DIM + c0;
    const uint4 p0 = *(const uint4*)(Hh + r0);
    const uint4 p1 = *(const uint4*)(Hh + r0 + 8);
    const uint4 q0 = *(const uint4*)(Hh + r1);
    const uint4 q1 = *(const uint4*)(Hh + r1 + 8);
    a[ 0] += blo(p0.x) + blo(q0.x);  a[ 1] += bhi(p0.x) + bhi(q0.x);
    a[ 2] += blo(p0.y) + blo(q0.y);  a[ 3] += bhi(p0.y) + bhi(q0.y);
    a[ 4] += blo(p0.z) + blo(q0.z);  a[ 5] += bhi(p0.z) + bhi(q0.z);
    a[ 6] += blo(p0.w) + blo(q0.w);  a[ 7] += bhi(p0.w) + bhi(q0.w);
    a[ 8] += blo(p1.x) + blo(q1.x);  a[ 9] += bhi(p1.x) + bhi(q1.x);
    a[10] += blo(p1.y) + blo(q1.y);  a[11] += bhi(p1.y) + bhi(q1.y);
    a[12] += blo(p1.z) + blo(q1.z);  a[13] += bhi(p1.z) + bhi(q1.z);
    a[14] += blo(p1.w) + blo(q1.w);  a[15] += bhi(p1.w) + bhi(q1.w);
  }
  if (e < end) {
    const size_t r0 = (size_t)ssrc[e] * K_DIM + c0;
    const uint4 p0 = *(const uint4*)(Hh + r0);
    const uint4 p1 = *(const uint4*)(Hh + r0 + 8);
    a[ 0] += blo(p0.x);  a[ 1] += bhi(p0.x);
    a[ 2] += blo(p0.y);  a[ 3] += bhi(p0.y);
    a[ 4] += blo(p0.z);  a[ 5] += bhi(p0.z);
    a[ 6] += blo(p0.w);  a[ 7] += bhi(p0.w);
    a[ 8] += blo(p1.x);  a[ 9] += bhi(p1.x);
    a[10] += blo(p1.y);  a[11] += bhi(p1.y);
    a[12] += blo(p1.z);  a[13] += bhi(p1.z);
    a[14] += blo(p1.w);  a[15] += bhi(p1.w);
  }
  const float sc = inv_deg[v];
  const size_t wo = (size_t)v * K_DIM + c0;
  #pragma unroll
  for (int g = 0; g < 4; ++g) {
    ushort4 oh;
    oh.x = f2b(a[4 * g + 0] * sc);
    oh.y = f2b(a[4 * g + 1] * sc);
    oh.z = f2b(a[4 * g + 2] * sc);
    oh.w = f2b(a[4 * g + 3] * sc);
    *(ushort4*)(Ah + wo + 4 * g) = oh;
  }
}

// ---------------------------------------------------------------- MFMA GEMM
// out = act( A1@W1 [+ A2@W2] + b ), bf16 activations, 16x16x32 bf16 MFMA.
// N-split: block = 128 rows x COLT cols (col0 = blockIdx.y*COLT).
// Round-8 change (round-6 counters: latency-bound, MfmaUtil 7%): keep the
// known-good inner skeleton but double loads-in-flight --
//   TWO:    stage BOTH weight slices (2x LDS), ONE barrier, interleave the
//           two phases -> 4 independent global A-loads per ks-iter.
//   single: 2x ks-unroll -> 4 A-loads per iter.
// bounds (256,6): cap 85 VGPR (est. live ~76). Spill tripwire: WRITE_SIZE >>
// output bytes -> revert to (256,4). DO NOT fully unroll outer loops
// (rounds 2-3: catastrophic spills).
// NO aliasing under n-split -- launcher rotates X/Y/Z planes.

template <int DOUT_FULL, int COLT, bool TWO, bool RELU, bool BF16_OUT>
__global__ __launch_bounds__(256, 6) void mfma_gemm_kernel(
    const ushort_t* __restrict__ A1, const ushort_t* __restrict__ A2,
    const ushort_t* __restrict__ W1sw, const ushort_t* __restrict__ W2sw,
    const float* __restrict__ bias,
    ushort_t* __restrict__ Obf, float* __restrict__ Ofp) {
  constexpr int NT  = COLT / 16;               // n-tiles per wave
  constexpr int SWN = (K_DIM / 8) * COLT * 8;  // ushorts per weight slice
  __shared__ ushort_t sW[(TWO ? 2 : 1) * SWN];

  const int tid  = threadIdx.x;
  const int wv   = tid >> 6;
  const int lane = tid & 63;
  const int lm   = lane & 15;    // m (A) / n (B) index within tile
  const int q    = lane >> 4;    // quad: k-group for A/B, row-group for C
  const int row0 = blockIdx.x * 128 + wv * 32;
  const int col0 = blockIdx.y * COLT;

  // stage weight column-slice(s): local [kg][nl][8] <- global [kg][col0+nl][8]
  for (int i = tid * 8; i < SWN; i += 2048) {
    const int kg = i / (COLT * 8);
    const int nl = (i >> 3) & (COLT - 1);
    *(uint4*)&sW[i] = *(const uint4*)&W1sw[kg * (DOUT_FULL * 8) + (col0 + nl) * 8];
    if (TWO)
      *(uint4*)&sW[SWN + i] = *(const uint4*)&W2sw[kg * (DOUT_FULL * 8) + (col0 + nl) * 8];
  }
  __syncthreads();

  int ra = row0 + lm;       ra = ra < N_NODES ? ra : N_NODES - 1;
  int rb = row0 + 16 + lm;  rb = rb < N_NODES ? rb : N_NODES - 1;
  const size_t off0 = (size_t)ra * K_DIM;
  const size_t off1 = (size_t)rb * K_DIM;

  v4f acc[2][NT];
  #pragma unroll
  for (int m = 0; m < 2; ++m)
    #pragma unroll
    for (int n = 0; n < NT; ++n) acc[m][n] = (v4f){0.f, 0.f, 0.f, 0.f};

  if (TWO) {
    // interleaved: acc += A1@W1 + A2@W2, 4 loads in flight per iter
    for (int ks = 0; ks < K_DIM / 32; ++ks) {
      const int ko = ks * 32 + q * 8;
      const v8s a0 = *(const v8s*)(A1 + off0 + ko);
      const v8s a1 = *(const v8s*)(A1 + off1 + ko);
      const v8s a2 = *(const v8s*)(A2 + off0 + ko);
      const v8s a3 = *(const v8s*)(A2 + off1 + ko);
      #pragma unroll
      for (int nt = 0; nt < NT; ++nt) {
        const int bi = ((ks * 4 + q) * COLT + nt * 16 + lm) * 8;
        const v8s b1 = *(const v8s*)&sW[bi];
        const v8s b2 = *(const v8s*)&sW[SWN + bi];
        acc[0][nt] = __builtin_amdgcn_mfma_f32_16x16x32_bf16(a0, b1, acc[0][nt], 0, 0, 0);
        acc[1][nt] = __builtin_amdgcn_mfma_f32_16x16x32_bf16(a1, b1, acc[1][nt], 0, 0, 0);
        acc[0][nt] = __builtin_amdgcn_mfma_f32_16x16x32_bf16(a2, b2, acc[0][nt], 0, 0, 0);
        acc[1][nt] = __builtin_amdgcn_mfma_f32_16x16x32_bf16(a3, b2, acc[1][nt], 0, 0, 0);
      }
    }
  } else {
    // single-W: 2x ks-unroll, 4 loads in flight per iter
    for (int ks = 0; ks < K_DIM / 64; ++ks) {
      const int ko = ks * 64 + q * 8;
      const v8s a0 = *(const v8s*)(A1 + off0 + ko);
      const v8s a1 = *(const v8s*)(A1 + off1 + ko);
      const v8s a2 = *(const v8s*)(A1 + off0 + ko + 32);
      const v8s a3 = *(const v8s*)(A1 + off1 + ko + 32);
      #pragma unroll
      for (int nt = 0; nt < NT; ++nt) {
        const int bi1 = ((ks * 8 + q) * COLT + nt * 16 + lm) * 8;
        const int bi2 = ((ks * 8 + q + 4) * COLT + nt * 16 + lm) * 8;
        const v8s b1 = *(const v8s*)&sW[bi1];
        const v8s b2 = *(const v8s*)&sW[bi2];
        acc[0][nt] = __builtin_amdgcn_mfma_f32_16x16x32_bf16(a0, b1, acc[0][nt], 0, 0, 0);
        acc[1][nt] = __builtin_amdgcn_mfma_f32_16x16x32_bf16(a1, b1, acc[1][nt], 0, 0, 0);
        acc[0][nt] = __builtin_amdgcn_mfma_f32_16x16x32_bf16(a2, b2, acc[0][nt], 0, 0, 0);
        acc[1][nt] = __builtin_amdgcn_mfma_f32_16x16x32_bf16(a3, b2, acc[1][nt], 0, 0, 0);
      }
    }
  }

  // ---- epilogue: C/D layout col=lane&15, row=quad*4+reg
  #pragma unroll
  for (int m = 0; m < 2; ++m) {
    #pragma unroll
    for (int nt = 0; nt < NT; ++nt) {
      const int col = col0 + nt * 16 + lm;
      const float bv = bias[col];
      #pragma unroll
      for (int r = 0; r < 4; ++r) {
        const int row = row0 + m * 16 + q * 4 + r;
        if (row < N_NODES) {
          float v = acc[m][nt][r] + bv;
          if (RELU) v = v > 0.f ? v : 0.f;
          if (BF16_OUT) Obf[(size_t)row * DOUT_FULL + col] = f2b(v);
          else          Ofp[(size_t)row * DOUT_FULL + col] = v;
        }
      }
    }
  }
}

// ---------------------------------------------------------------- launcher

extern "C" void kernel_launch(void* const* d_in, const int* in_sizes, int n_in,
                              void* d_out, int out_size, void* d_ws, size_t ws_size,
                              hipStream_t stream) {
  const float* x        = (const float*)d_in[0];
  const int*   src      = (const int*)d_in[1];
  const int*   dst      = (const int*)d_in[2];
  const float* w_self0  = (const float*)d_in[3];
  const float* b_self0  = (const float*)d_in[4];
  const float* w_neigh0 = (const float*)d_in[5];
  const float* fc_w     = (const float*)d_in[6];
  const float* fc_b     = (const float*)d_in[7];
  const float* fc2_w    = (const float*)d_in[8];
  const float* fc2_b    = (const float*)d_in[9];
  const float* w_self1  = (const float*)d_in[10];
  const float* b_self1  = (const float*)d_in[11];
  const float* w_neigh1 = (const float*)d_in[12];
  const float* w_self2  = (const float*)d_in[13];
  const float* b_self2  = (const float*)d_in[14];
  const float* w_neigh2 = (const float*)d_in[15];

  char* p = (char*)d_ws;
  auto carve = [&](size_t bytes) {
    void* q = (void*)p;
    p += (bytes + 511) & ~(size_t)511;
    return q;
  };
  const size_t PLANE = (size_t)N_NODES * K_DIM * sizeof(ushort_t);   // 25.6 MB
  ushort_t* X   = (ushort_t*)carve(PLANE);
  ushort_t* Y   = (ushort_t*)carve(PLANE);
  ushort_t* Z   = (ushort_t*)carve(PLANE);
  ushort_t* ws0 = (ushort_t*)carve(K_DIM * 128 * 2);
  ushort_t* wn0 = (ushort_t*)carve(K_DIM * 128 * 2);
  ushort_t* wfc = (ushort_t*)carve(K_DIM * 128 * 2);
  ushort_t* wf2 = (ushort_t*)carve(K_DIM * 128 * 2);
  ushort_t* ws1 = (ushort_t*)carve(K_DIM * 128 * 2);
  ushort_t* wn1 = (ushort_t*)carve(K_DIM * 128 * 2);
  ushort_t* ws2 = (ushort_t*)carve(K_DIM * 64 * 2);
  ushort_t* wn2 = (ushort_t*)carve(K_DIM * 64 * 2);
  int*   ssrc    = (int*)carve((size_t)N_EDGES * 4);
  int*   row_ptr = (int*)carve((size_t)(N_NODES + 1) * 4);
  int*   cursor  = (int*)carve((size_t)N_NODES * 4);
  int*   deg     = (int*)carve((size_t)N_NODES * 4);
  int*   excl    = (int*)carve((size_t)N_NODES * 4);
  int*   parts   = (int*)carve(512 * 4);
  float* inv_deg = (float*)carve((size_t)N_NODES * 4);

  // ---- CSR build (by dst)
  hipMemsetAsync(deg, 0, (size_t)N_NODES * 4, stream);
  const int EB = (N_EDGES + 255) / 256;
  deg_kernel<<<EB, 256, 0, stream>>>(dst, deg);
  scan1_kernel<<<NPART, 256, 0, stream>>>(deg, excl, parts);
  scan2_kernel<<<1, 512, 0, stream>>>(parts);
  scan3_kernel<<<((N_NODES + 1) + 255) / 256, 256, 0, stream>>>(excl, parts, deg,
                                                                row_ptr, cursor, inv_deg);
  fill_kernel<<<EB, 256, 0, stream>>>(src, dst, cursor, ssrc);

  // ---- prep: cast x to bf16; swizzle all 8 weights in one launch
  cast_kernel<<<(N_NODES * K_DIM / 4 + 255) / 256, 256, 0, stream>>>(x, X);
  swizzle_all_kernel<<<dim3(64, 1, 8), 256, 0, stream>>>(
      w_self0, w_neigh0, fc_w, fc2_w, w_self1, w_neigh1, w_self2, w_neigh2,
      ws0, wn0, wfc, wf2, ws1, wn1, ws2, wn2);

  // ---- network: strict no-alias rotation over X/Y/Z (n-split requirement)
  const int AB = (N_NODES + 31) / 32;
  const int GB = (N_NODES + 127) / 128;
  const dim3 G2(GB, 2);   // 128-wide layers: COLT=64, grid y=2
  const dim3 G2b(GB, 2);  // final layer: COLT=32, grid y=2

  // layer 0: agg(X)->Y ; relu(X@Ws0 + Y@Wn0 + b) -> Z
  agg_kernel<<<AB, 256, 0, stream>>>(X, row_ptr, ssrc, inv_deg, Y);
  mfma_gemm_kernel<128, 64, true, true, true><<<G2, 256, 0, stream>>>(
      X, Y, ws0, wn0, b_self0, Z, nullptr);
  // NGNN fc layers: Z -> X -> Y
  mfma_gemm_kernel<128, 64, false, true, true><<<G2, 256, 0, stream>>>(
      Z, nullptr, wfc, nullptr, fc_b, X, nullptr);
  mfma_gemm_kernel<128, 64, false, true, true><<<G2, 256, 0, stream>>>(
      X, nullptr, wf2, nullptr, fc2_b, Y, nullptr);
  // layer 1: agg(Y)->X ; relu(Y@Ws1 + X@Wn1 + b) -> Z
  agg_kernel<<<AB, 256, 0, stream>>>(Y, row_ptr, ssrc, inv_deg, X);
  mfma_gemm_kernel<128, 64, true, true, true><<<G2, 256, 0, stream>>>(
      Y, X, ws1, wn1, b_self1, Z, nullptr);
  // layer 2: agg(Z)->Y ; Z@Ws2 + Y@Wn2 + b -> d_out (fp32, DOUT=64, COLT=32)
  agg_kernel<<<AB, 256, 0, stream>>>(Z, row_ptr, ssrc, inv_deg, Y);
  mfma_gemm_kernel<64, 32, true, false, false><<<G2b, 256, 0, stream>>>(
      Z, Y, ws2, wn2, b_self2, nullptr, (float*)d_out);
}

// Round 9
// 368.419 us; speedup vs baseline: 1.0420x; 1.0420x over previous
//
#include <hip/hip_runtime.h>

#define N_NODES 100000
#define N_EDGES 600000
#define K_DIM   128
#define NPART   ((N_NODES + 255) / 256)   // 391 scan blocks

typedef unsigned short ushort_t;
typedef short v8s __attribute__((ext_vector_type(8)));   // 8 bf16 = 4 VGPRs
typedef float v4f __attribute__((ext_vector_type(4)));   // MFMA acc frag

// fp32 -> bf16 round-to-nearest-even (inputs are finite; no NaN handling)
__device__ __forceinline__ ushort_t f2b(float f) {
  unsigned u = __builtin_bit_cast(unsigned, f);
  unsigned r = u + 0x7FFFu + ((u >> 16) & 1u);
  return (ushort_t)(r >> 16);
}
__device__ __forceinline__ float b2f(ushort_t h) {
  return __builtin_bit_cast(float, (unsigned)h << 16);
}
// unpack a uint holding two bf16 (little-endian: element0 = low half)
__device__ __forceinline__ float blo(unsigned u) {
  return __builtin_bit_cast(float, u << 16);
}
__device__ __forceinline__ float bhi(unsigned u) {
  return __builtin_bit_cast(float, u & 0xFFFF0000u);
}

// ---------------------------------------------------------------- CSR build

__global__ void deg_kernel(const int* __restrict__ dst, int* __restrict__ deg) {
  int e = blockIdx.x * blockDim.x + threadIdx.x;
  if (e < N_EDGES) atomicAdd(&deg[dst[e]], 1);
}

__global__ void scan1_kernel(const int* __restrict__ deg, int* __restrict__ excl,
                             int* __restrict__ partials) {
  __shared__ int s[256];
  int t = threadIdx.x, i = blockIdx.x * 256 + t;
  int v = (i < N_NODES) ? deg[i] : 0;
  s[t] = v;
  __syncthreads();
  for (int off = 1; off < 256; off <<= 1) {
    int x = (t >= off) ? s[t - off] : 0;
    __syncthreads();
    s[t] += x;
    __syncthreads();
  }
  if (i < N_NODES) excl[i] = s[t] - v;
  if (t == 255) partials[blockIdx.x] = s[t];
}

__global__ void scan2_kernel(int* __restrict__ partials) {
  __shared__ int s[512];
  int t = threadIdx.x;
  int v = (t < NPART) ? partials[t] : 0;
  s[t] = v;
  __syncthreads();
  for (int off = 1; off < 512; off <<= 1) {
    int x = (t >= off) ? s[t - off] : 0;
    __syncthreads();
    s[t] += x;
    __syncthreads();
  }
  if (t < NPART) partials[t] = s[t] - v;   // exclusive block offsets
}

__global__ void scan3_kernel(const int* __restrict__ excl, const int* __restrict__ partials,
                             const int* __restrict__ deg, int* __restrict__ row_ptr,
                             int* __restrict__ cursor, float* __restrict__ inv_deg) {
  int i = blockIdx.x * blockDim.x + threadIdx.x;
  if (i < N_NODES) {
    int rp = excl[i] + partials[i >> 8];
    row_ptr[i] = rp;
    cursor[i] = rp;
    inv_deg[i] = 1.0f / (float)(deg[i] > 1 ? deg[i] : 1);
  } else if (i == N_NODES) {
    row_ptr[N_NODES] = N_EDGES;
  }
}

__global__ void fill_kernel(const int* __restrict__ src, const int* __restrict__ dst,
                            int* __restrict__ cursor, int* __restrict__ ssrc) {
  int e = blockIdx.x * blockDim.x + threadIdx.x;
  if (e < N_EDGES) {
    int p = atomicAdd(&cursor[dst[e]], 1);
    ssrc[p] = src[e];
  }
}

// ---------------------------------------------------------------- prep

// x (fp32) -> bf16 plane
__global__ void cast_kernel(const float* __restrict__ X, ushort_t* __restrict__ Xb) {
  int i = (blockIdx.x * 256 + threadIdx.x) * 4;
  if (i >= N_NODES * K_DIM) return;
  float4 v = *(const float4*)(X + i);
  ushort4 h;
  h.x = f2b(v.x); h.y = f2b(v.y); h.z = f2b(v.z); h.w = f2b(v.w);
  *(ushort4*)(Xb + i) = h;
}

// All 8 weights swizzled in ONE launch (blockIdx.z selects the weight).
// Layout: sw[(k>>3)*DOUT*8 + n*8 + (k&7)] -> lane's 8 k-values contiguous.
__global__ void swizzle_all_kernel(
    const float* __restrict__ w0, const float* __restrict__ w1,
    const float* __restrict__ w2, const float* __restrict__ w3,
    const float* __restrict__ w4, const float* __restrict__ w5,
    const float* __restrict__ w6, const float* __restrict__ w7,
    ushort_t* __restrict__ s0, ushort_t* __restrict__ s1,
    ushort_t* __restrict__ s2, ushort_t* __restrict__ s3,
    ushort_t* __restrict__ s4, ushort_t* __restrict__ s5,
    ushort_t* __restrict__ s6, ushort_t* __restrict__ s7) {
  const int z = blockIdx.z;
  const float* W;
  ushort_t* S;
  int dout = 128;
  switch (z) {
    case 0: W = w0; S = s0; break;
    case 1: W = w1; S = s1; break;
    case 2: W = w2; S = s2; break;
    case 3: W = w3; S = s3; break;
    case 4: W = w4; S = s4; break;
    case 5: W = w5; S = s5; break;
    case 6: W = w6; S = s6; dout = 64; break;
    default: W = w7; S = s7; dout = 64; break;
  }
  int t = blockIdx.x * 256 + threadIdx.x;
  if (t >= K_DIM * dout) return;
  int k = t / dout, n = t % dout;
  S[(k >> 3) * (dout * 8) + n * 8 + (k & 7)] = f2b(W[t]);
}

// ---------------------------------------------------------------- aggregate
// AGG[v] = inv_deg[v] * sum_{u->v} H[u]  (bf16 in, bf16 out -- single plane).
// 8 lanes/row (16 cols each), 32 rows/block, 2-edge unroll for MLP,
// max-occupancy launch bounds (VGPR 28 -> 8 waves/EU fits).

__global__ __launch_bounds__(256, 8) void agg_kernel(
    const ushort_t* __restrict__ Hh,
    const int* __restrict__ row_ptr, const int* __restrict__ ssrc,
    const float* __restrict__ inv_deg, ushort_t* __restrict__ Ah) {
  const int tid = threadIdx.x;
  const int c0  = (tid & 7) * 16;   // 16 columns per lane
  const int r   = tid >> 3;
  const int v   = blockIdx.x * 32 + r;
  if (v >= N_NODES) return;

  float a[16];
  #pragma unroll
  for (int i = 0; i < 16; ++i) a[i] = 0.f;

  const int beg = row_ptr[v], end = row_ptr[v + 1];
  int e = beg;
  for (; e + 2 <= end; e += 2) {
    const size_t r0 = (size_t)ssrc[e] * K_DIM + c0;
    const size_t r1 = (size_t)ssrc[e + 1] * K_DIM + c0;
    const uint4 p0 = *(const uint4*)(Hh + r0);
    const uint4 p1 = *(const uint4*)(Hh + r0 + 8);
    const uint4 q0 = *(const uint4*)(Hh + r1);
    const uint4 q1 = *(const uint4*)(Hh + r1 + 8);
    a[ 0] += blo(p0.x) + blo(q0.x);  a[ 1] += bhi(p0.x) + bhi(q0.x);
    a[ 2] += blo(p0.y) + blo(q0.y);  a[ 3] += bhi(p0.y) + bhi(q0.y);
    a[ 4] += blo(p0.z) + blo(q0.z);  a[ 5] += bhi(p0.z) + bhi(q0.z);
    a[ 6] += blo(p0.w) + blo(q0.w);  a[ 7] += bhi(p0.w) + bhi(q0.w);
    a[ 8] += blo(p1.x) + blo(q1.x);  a[ 9] += bhi(p1.x) + bhi(q1.x);
    a[10] += blo(p1.y) + blo(q1.y);  a[11] += bhi(p1.y) + bhi(q1.y);
    a[12] += blo(p1.z) + blo(q1.z);  a[13] += bhi(p1.z) + bhi(q1.z);
    a[14] += blo(p1.w) + blo(q1.w);  a[15] += bhi(p1.w) + bhi(q1.w);
  }
  if (e < end) {
    const size_t r0 = (size_t)ssrc[e] * K_DIM + c0;
    const uint4 p0 = *(const uint4*)(Hh + r0);
    const uint4 p1 = *(const uint4*)(Hh + r0 + 8);
    a[ 0] += blo(p0.x);  a[ 1] += bhi(p0.x);
    a[ 2] += blo(p0.y);  a[ 3] += bhi(p0.y);
    a[ 4] += blo(p0.z);  a[ 5] += bhi(p0.z);
    a[ 6] += blo(p0.w);  a[ 7] += bhi(p0.w);
    a[ 8] += blo(p1.x);  a[ 9] += bhi(p1.x);
    a[10] += blo(p1.y);  a[11] += bhi(p1.y);
    a[12] += blo(p1.z);  a[13] += bhi(p1.z);
    a[14] += blo(p1.w);  a[15] += bhi(p1.w);
  }
  const float sc = inv_deg[v];
  const size_t wo = (size_t)v * K_DIM + c0;
  #pragma unroll
  for (int g = 0; g < 4; ++g) {
    ushort4 oh;
    oh.x = f2b(a[4 * g + 0] * sc);
    oh.y = f2b(a[4 * g + 1] * sc);
    oh.z = f2b(a[4 * g + 2] * sc);
    oh.w = f2b(a[4 * g + 3] * sc);
    *(ushort4*)(Ah + wo + 4 * g) = oh;
  }
}

// ---------------------------------------------------------------- MFMA GEMM
// ROUND-7 VERSION RESTORED VERBATIM (round-8's interleave/2xLDS/(256,6) was
// a ~10 us regression -- after the n-split these kernels are not MLP-bound).
// out = act( A1@W1 [+ A2@W2] + b ), bf16 activations, 16x16x32 bf16 MFMA.
// N-split: block = 128 rows x 64 cols. NO aliasing under n-split -- launcher
// rotates X/Y/Z planes. DO NOT unroll outer loops / register-prefetch
// (rounds 2-3: catastrophic spills; tripwire = WRITE_SIZE >> output bytes).

template <int DOUT_FULL, bool TWO, bool RELU, bool BF16_OUT>
__global__ __launch_bounds__(256, 4) void mfma_gemm_kernel(
    const ushort_t* __restrict__ A1, const ushort_t* __restrict__ A2,
    const ushort_t* __restrict__ W1sw, const ushort_t* __restrict__ W2sw,
    const float* __restrict__ bias,
    ushort_t* __restrict__ Obf, float* __restrict__ Ofp) {
  constexpr int COLT = 64;           // cols per block
  constexpr int NT   = COLT / 16;    // 4 n-tiles per wave
  constexpr int SWN  = (K_DIM / 8) * COLT * 8;   // 8192 ushorts = 16 KB
  __shared__ ushort_t sW[SWN];

  const int tid  = threadIdx.x;
  const int wv   = tid >> 6;
  const int lane = tid & 63;
  const int lm   = lane & 15;    // m (A) / n (B) index within tile
  const int q    = lane >> 4;    // quad: k-group for A/B, row-group for C
  const int row0 = blockIdx.x * 128 + wv * 32;
  const int col0 = blockIdx.y * COLT;

  // stage W1 column-slice: local [kg][nl][8] <- global [kg][col0+nl][8]
  for (int i = tid * 8; i < SWN; i += 2048) {
    const int kg = i / (COLT * 8);
    const int nl = (i >> 3) & (COLT - 1);
    *(uint4*)&sW[i] = *(const uint4*)&W1sw[kg * (DOUT_FULL * 8) + (col0 + nl) * 8];
  }
  __syncthreads();

  int ra = row0 + lm;       ra = ra < N_NODES ? ra : N_NODES - 1;
  int rb = row0 + 16 + lm;  rb = rb < N_NODES ? rb : N_NODES - 1;
  const size_t off0 = (size_t)ra * K_DIM;
  const size_t off1 = (size_t)rb * K_DIM;

  v4f acc[2][NT];
  #pragma unroll
  for (int m = 0; m < 2; ++m)
    #pragma unroll
    for (int n = 0; n < NT; ++n) acc[m][n] = (v4f){0.f, 0.f, 0.f, 0.f};

  // ---- phase 1: A1 @ W1
  for (int ks = 0; ks < K_DIM / 32; ++ks) {
    const int ko = ks * 32 + q * 8;
    const v8s a0 = *(const v8s*)(A1 + off0 + ko);
    const v8s a1 = *(const v8s*)(A1 + off1 + ko);
    #pragma unroll
    for (int nt = 0; nt < NT; ++nt) {
      const v8s b = *(const v8s*)&sW[((ks * 4 + q) * COLT + nt * 16 + lm) * 8];
      acc[0][nt] = __builtin_amdgcn_mfma_f32_16x16x32_bf16(a0, b, acc[0][nt], 0, 0, 0);
      acc[1][nt] = __builtin_amdgcn_mfma_f32_16x16x32_bf16(a1, b, acc[1][nt], 0, 0, 0);
    }
  }

  if (TWO) {
    __syncthreads();
    for (int i = tid * 8; i < SWN; i += 2048) {
      const int kg = i / (COLT * 8);
      const int nl = (i >> 3) & (COLT - 1);
      *(uint4*)&sW[i] = *(const uint4*)&W2sw[kg * (DOUT_FULL * 8) + (col0 + nl) * 8];
    }
    __syncthreads();

    // ---- phase 2: A2 @ W2
    for (int ks = 0; ks < K_DIM / 32; ++ks) {
      const int ko = ks * 32 + q * 8;
      const v8s a0 = *(const v8s*)(A2 + off0 + ko);
      const v8s a1 = *(const v8s*)(A2 + off1 + ko);
      #pragma unroll
      for (int nt = 0; nt < NT; ++nt) {
        const v8s b = *(const v8s*)&sW[((ks * 4 + q) * COLT + nt * 16 + lm) * 8];
        acc[0][nt] = __builtin_amdgcn_mfma_f32_16x16x32_bf16(a0, b, acc[0][nt], 0, 0, 0);
        acc[1][nt] = __builtin_amdgcn_mfma_f32_16x16x32_bf16(a1, b, acc[1][nt], 0, 0, 0);
      }
    }
  }

  // ---- epilogue: C/D layout col=lane&15, row=quad*4+reg
  #pragma unroll
  for (int m = 0; m < 2; ++m) {
    #pragma unroll
    for (int nt = 0; nt < NT; ++nt) {
      const int col = col0 + nt * 16 + lm;
      const float bv = bias[col];
      #pragma unroll
      for (int r = 0; r < 4; ++r) {
        const int row = row0 + m * 16 + q * 4 + r;
        if (row < N_NODES) {
          float v = acc[m][nt][r] + bv;
          if (RELU) v = v > 0.f ? v : 0.f;
          if (BF16_OUT) Obf[(size_t)row * DOUT_FULL + col] = f2b(v);
          else          Ofp[(size_t)row * DOUT_FULL + col] = v;
        }
      }
    }
  }
}

// ---------------------------------------------------------------- fused FC
// O = relu( relu(A@W1 + b1) @ W2 + b2 ), both 128x128.  fc2's K-dim == fc's
// N-dim, so a full-width block (128 rows x 128 cols) computes H1 into
// registers, round-trips it through padded LDS (C-layout -> A-layout, the
// flash-attention P-matrix pattern), restages W2 into the weight buffer, and
// finishes without touching global for H1. Saves one dispatch + 51 MB of
// plane traffic. H1 row stride 136 (+8 pad) -> bank 4*row mod 32, 2-way
// aliasing = free. Precision identical to the two-kernel path (H1 is
// bf16(relu(.)) either way). LDS 66 KB -> 2 blocks/CU.

__global__ __launch_bounds__(256, 2) void fused_fc_kernel(
    const ushort_t* __restrict__ A,
    const ushort_t* __restrict__ W1sw, const ushort_t* __restrict__ W2sw,
    const float* __restrict__ b1, const float* __restrict__ b2,
    ushort_t* __restrict__ O) {
  constexpr int NT = 8;     // full 128 cols per wave
  constexpr int HP = 136;   // padded H1 row stride (bf16 elems)
  __shared__ ushort_t bufW[K_DIM * 128];   // 32 KB weight slice
  __shared__ ushort_t bufH[128 * HP];      // 34 KB H1 staging

  const int tid   = threadIdx.x;
  const int wv    = tid >> 6;
  const int lane  = tid & 63;
  const int lm    = lane & 15;
  const int q     = lane >> 4;
  const int lrow0 = wv * 32;                 // local row base
  const int row0  = blockIdx.x * 128 + lrow0;

  // stage W1 (full width)
  for (int i = tid * 8; i < K_DIM * 128; i += 2048)
    *(uint4*)&bufW[i] = *(const uint4*)&W1sw[i];
  __syncthreads();

  int ra = row0 + lm;       ra = ra < N_NODES ? ra : N_NODES - 1;
  int rb = row0 + 16 + lm;  rb = rb < N_NODES ? rb : N_NODES - 1;
  const size_t off0 = (size_t)ra * K_DIM;
  const size_t off1 = (size_t)rb * K_DIM;

  v4f acc[2][NT];
  #pragma unroll
  for (int m = 0; m < 2; ++m)
    #pragma unroll
    for (int n = 0; n < NT; ++n) acc[m][n] = (v4f){0.f, 0.f, 0.f, 0.f};

  // ---- phase 1: A @ W1
  for (int ks = 0; ks < K_DIM / 32; ++ks) {
    const int ko = ks * 32 + q * 8;
    const v8s a0 = *(const v8s*)(A + off0 + ko);
    const v8s a1 = *(const v8s*)(A + off1 + ko);
    #pragma unroll
    for (int nt = 0; nt < NT; ++nt) {
      const v8s b = *(const v8s*)&bufW[((ks * 4 + q) * 128 + nt * 16 + lm) * 8];
      acc[0][nt] = __builtin_amdgcn_mfma_f32_16x16x32_bf16(a0, b, acc[0][nt], 0, 0, 0);
      acc[1][nt] = __builtin_amdgcn_mfma_f32_16x16x32_bf16(a1, b, acc[1][nt], 0, 0, 0);
    }
  }
  __syncthreads();   // all waves finished reading bufW (phase 1)

  // ---- H1 = bf16(relu(acc + b1)) -> bufH ; restage W2 -> bufW
  #pragma unroll
  for (int m = 0; m < 2; ++m) {
    #pragma unroll
    for (int nt = 0; nt < NT; ++nt) {
      const int col = nt * 16 + lm;
      const float bv = b1[col];
      #pragma unroll
      for (int r = 0; r < 4; ++r) {
        float v = acc[m][nt][r] + bv;
        v = v > 0.f ? v : 0.f;
        bufH[(lrow0 + m * 16 + q * 4 + r) * HP + col] = f2b(v);
        acc[m][nt][r] = 0.f;   // reuse accumulators for phase 2
      }
    }
  }
  for (int i = tid * 8; i < K_DIM * 128; i += 2048)
    *(uint4*)&bufW[i] = *(const uint4*)&W2sw[i];
  __syncthreads();

  // ---- phase 2: H1 @ W2 (A-frags from LDS, 16 B aligned: HP*2 % 16 == 0)
  for (int ks = 0; ks < K_DIM / 32; ++ks) {
    const int ko = ks * 32 + q * 8;
    const v8s a0 = *(const v8s*)&bufH[(lrow0 + lm) * HP + ko];
    const v8s a1 = *(const v8s*)&bufH[(lrow0 + 16 + lm) * HP + ko];
    #pragma unroll
    for (int nt = 0; nt < NT; ++nt) {
      const v8s b = *(const v8s*)&bufW[((ks * 4 + q) * 128 + nt * 16 + lm) * 8];
      acc[0][nt] = __builtin_amdgcn_mfma_f32_16x16x32_bf16(a0, b, acc[0][nt], 0, 0, 0);
      acc[1][nt] = __builtin_amdgcn_mfma_f32_16x16x32_bf16(a1, b, acc[1][nt], 0, 0, 0);
    }
  }

  // ---- epilogue: relu(acc + b2) -> O (bf16)
  #pragma unroll
  for (int m = 0; m < 2; ++m) {
    #pragma unroll
    for (int nt = 0; nt < NT; ++nt) {
      const int col = nt * 16 + lm;
      const float bv = b2[col];
      #pragma unroll
      for (int r = 0; r < 4; ++r) {
        const int row = row0 + m * 16 + q * 4 + r;
        if (row < N_NODES) {
          float v = acc[m][nt][r] + bv;
          v = v > 0.f ? v : 0.f;
          O[(size_t)row * 128 + col] = f2b(v);
        }
      }
    }
  }
}

// ---------------------------------------------------------------- launcher

extern "C" void kernel_launch(void* const* d_in, const int* in_sizes, int n_in,
                              void* d_out, int out_size, void* d_ws, size_t ws_size,
                              hipStream_t stream) {
  const float* x        = (const float*)d_in[0];
  const int*   src      = (const int*)d_in[1];
  const int*   dst      = (const int*)d_in[2];
  const float* w_self0  = (const float*)d_in[3];
  const float* b_self0  = (const float*)d_in[4];
  const float* w_neigh0 = (const float*)d_in[5];
  const float* fc_w     = (const float*)d_in[6];
  const float* fc_b     = (const float*)d_in[7];
  const float* fc2_w    = (const float*)d_in[8];
  const float* fc2_b    = (const float*)d_in[9];
  const float* w_self1  = (const float*)d_in[10];
  const float* b_self1  = (const float*)d_in[11];
  const float* w_neigh1 = (const float*)d_in[12];
  const float* w_self2  = (const float*)d_in[13];
  const float* b_self2  = (const float*)d_in[14];
  const float* w_neigh2 = (const float*)d_in[15];

  char* p = (char*)d_ws;
  auto carve = [&](size_t bytes) {
    void* q = (void*)p;
    p += (bytes + 511) & ~(size_t)511;
    return q;
  };
  const size_t PLANE = (size_t)N_NODES * K_DIM * sizeof(ushort_t);   // 25.6 MB
  ushort_t* X   = (ushort_t*)carve(PLANE);
  ushort_t* Y   = (ushort_t*)carve(PLANE);
  ushort_t* Z   = (ushort_t*)carve(PLANE);
  ushort_t* ws0 = (ushort_t*)carve(K_DIM * 128 * 2);
  ushort_t* wn0 = (ushort_t*)carve(K_DIM * 128 * 2);
  ushort_t* wfc = (ushort_t*)carve(K_DIM * 128 * 2);
  ushort_t* wf2 = (ushort_t*)carve(K_DIM * 128 * 2);
  ushort_t* ws1 = (ushort_t*)carve(K_DIM * 128 * 2);
  ushort_t* wn1 = (ushort_t*)carve(K_DIM * 128 * 2);
  ushort_t* ws2 = (ushort_t*)carve(K_DIM * 64 * 2);
  ushort_t* wn2 = (ushort_t*)carve(K_DIM * 64 * 2);
  int*   ssrc    = (int*)carve((size_t)N_EDGES * 4);
  int*   row_ptr = (int*)carve((size_t)(N_NODES + 1) * 4);
  int*   cursor  = (int*)carve((size_t)N_NODES * 4);
  int*   deg     = (int*)carve((size_t)N_NODES * 4);
  int*   excl    = (int*)carve((size_t)N_NODES * 4);
  int*   parts   = (int*)carve(512 * 4);
  float* inv_deg = (float*)carve((size_t)N_NODES * 4);

  // ---- CSR build (by dst)
  hipMemsetAsync(deg, 0, (size_t)N_NODES * 4, stream);
  const int EB = (N_EDGES + 255) / 256;
  deg_kernel<<<EB, 256, 0, stream>>>(dst, deg);
  scan1_kernel<<<NPART, 256, 0, stream>>>(deg, excl, parts);
  scan2_kernel<<<1, 512, 0, stream>>>(parts);
  scan3_kernel<<<((N_NODES + 1) + 255) / 256, 256, 0, stream>>>(excl, parts, deg,
                                                                row_ptr, cursor, inv_deg);
  fill_kernel<<<EB, 256, 0, stream>>>(src, dst, cursor, ssrc);

  // ---- prep: cast x to bf16; swizzle all 8 weights in one launch
  cast_kernel<<<(N_NODES * K_DIM / 4 + 255) / 256, 256, 0, stream>>>(x, X);
  swizzle_all_kernel<<<dim3(64, 1, 8), 256, 0, stream>>>(
      w_self0, w_neigh0, fc_w, fc2_w, w_self1, w_neigh1, w_self2, w_neigh2,
      ws0, wn0, wfc, wf2, ws1, wn1, ws2, wn2);

  // ---- network: strict no-alias rotation over X/Y/Z (n-split requirement)
  const int AB = (N_NODES + 31) / 32;
  const int GB = (N_NODES + 127) / 128;
  const dim3 G2(GB, 2), G1(GB, 1);

  // layer 0: agg(X)->Y ; relu(X@Ws0 + Y@Wn0 + b) -> Z
  agg_kernel<<<AB, 256, 0, stream>>>(X, row_ptr, ssrc, inv_deg, Y);
  mfma_gemm_kernel<128, true, true, true><<<G2, 256, 0, stream>>>(
      X, Y, ws0, wn0, b_self0, Z, nullptr);
  // NGNN fc layers, fused: Z -> Y
  fused_fc_kernel<<<G1, 256, 0, stream>>>(Z, wfc, wf2, fc_b, fc2_b, Y);
  // layer 1: agg(Y)->X ; relu(Y@Ws1 + X@Wn1 + b) -> Z
  agg_kernel<<<AB, 256, 0, stream>>>(Y, row_ptr, ssrc, inv_deg, X);
  mfma_gemm_kernel<128, true, true, true><<<G2, 256, 0, stream>>>(
      Y, X, ws1, wn1, b_self1, Z, nullptr);
  // layer 2: agg(Z)->Y ; Z@Ws2 + Y@Wn2 + b -> d_out (fp32, DOUT=64)
  agg_kernel<<<AB, 256, 0, stream>>>(Z, row_ptr, ssrc, inv_deg, Y);
  mfma_gemm_kernel<64, true, false, false><<<G1, 256, 0, stream>>>(
      Z, Y, ws2, wn2, b_self2, nullptr, (float*)d_out);
}